// Round 11
// baseline (316.021 us; speedup 1.0000x reference)
//
#include <hip/hip_runtime.h>

typedef _Float16 f16x8 __attribute__((ext_vector_type(8)));
typedef _Float16 f16x4 __attribute__((ext_vector_type(4)));
typedef _Float16 f16x2 __attribute__((ext_vector_type(2)));
typedef float    f32x4 __attribute__((ext_vector_type(4)));
typedef float    f32x16 __attribute__((ext_vector_type(16)));
typedef unsigned u32x4 __attribute__((ext_vector_type(4)));
typedef unsigned long long u64;

constexpr int Bc = 4, Hc = 16, Sc = 2048, Dc = 64;
constexpr int KVBLK = 64;
constexpr int NKV = Sc / KVBLK;   // 32
constexpr int QB  = 128;          // q rows per block (4 groups x 32, 2 kt-waves each)
constexpr int NQT = Sc / QB;      // 16
constexpr int NQ  = 32;           // mask row-block granularity (64 rows)

__device__ __forceinline__ float fast_exp2(float x) {
#if __has_builtin(__builtin_amdgcn_exp2f)
  return __builtin_amdgcn_exp2f(x);
#else
  return exp2f(x);
#endif
}

__device__ __forceinline__ void gload16(const void* g, void* l) {
  __builtin_amdgcn_global_load_lds(
      (const __attribute__((address_space(1))) void*)g,
      (__attribute__((address_space(3))) void*)l, 16, 0, 0);
}

__device__ __forceinline__ f32x16 mfma32(f16x8 a, f16x8 b, f32x16 c) {
  return __builtin_amdgcn_mfma_f32_32x32x16_f16(a, b, c, 0, 0, 0);
}

__device__ __forceinline__ unsigned pkrtz(float x, float y) {
  return __builtin_bit_cast(unsigned, __builtin_amdgcn_cvt_pkrtz(x, y));
}

__device__ __forceinline__ float dot2acc(unsigned pk, float acc) {
#if __has_builtin(__builtin_amdgcn_fdot2)
  const f16x2 one2 = {(_Float16)1.f, (_Float16)1.f};
  return __builtin_amdgcn_fdot2(__builtin_bit_cast(f16x2, pk), one2, acc, false);
#else
  const f16x2 v = __builtin_bit_cast(f16x2, pk);
  return acc + (float)v[0] + (float)v[1];
#endif
}

__device__ __forceinline__ f32x16 zero16() {
  f32x16 z;
  #pragma unroll
  for (int i = 0; i < 16; ++i) z[i] = 0.f;
  return z;
}

// ---- Prepass A: K fp32 [bh][s][d] -> fp16 XOR-swizzled tiles ----
// tile row r (key), stored chunk s holds logical chunk s^(r&7) (8 halves of d)
__global__ __launch_bounds__(256)
void cvt_k_sw(const float* __restrict__ K, _Float16* __restrict__ Ko) {
  const int tile = blockIdx.x;              // bh*32 + kvt
  const int t = threadIdx.x;
  const float* src = K + (size_t)tile * 4096;
  _Float16* dst = Ko + (size_t)tile * 4096;
  #pragma unroll
  for (int cc = 0; cc < 2; ++cc) {
    const int c = t + cc * 256;
    const int r = c >> 3, s = c & 7;
    const int ss = s ^ (r & 7);
    const float* p = src + r * 64 + ss * 8;
    const float4 a = *(const float4*)p;
    const float4 b2 = *(const float4*)(p + 4);
    f16x8 h = {(_Float16)a.x, (_Float16)a.y, (_Float16)a.z, (_Float16)a.w,
               (_Float16)b2.x, (_Float16)b2.y, (_Float16)b2.z, (_Float16)b2.w};
    *(f16x8*)(dst + (size_t)c * 8) = h;
  }
}

// ---- Prepass B: V -> fp16 transposed [d][kappa], key = bitswap23(kappa), swizzled ----
__global__ __launch_bounds__(256)
void cvt_v_sw2(const float* __restrict__ V, _Float16* __restrict__ Vo) {
  __shared__ float tile[64][65];            // [key][d]
  const int tb = blockIdx.x;                // bh*32 + kvt
  const int t = threadIdx.x;
  const float* src = V + (size_t)tb * 4096;
  {
    const int r = t >> 2, c0 = (t & 3) * 16;
    #pragma unroll
    for (int j = 0; j < 16; j += 4)
      *(float4*)&tile[r][c0 + j] = *(const float4*)(src + r * 64 + c0 + j);
  }
  __syncthreads();
  _Float16* dst = Vo + (size_t)tb * 4096;
  #pragma unroll
  for (int cc = 0; cc < 2; ++cc) {
    const int c = t + cc * 256;
    const int d = c >> 3, cpos = c & 7;
    const int cl = cpos ^ (d & 7);          // logical chunk after XOR swizzle
    f16x8 h;
    #pragma unroll
    for (int e = 0; e < 8; ++e) {
      const int kap = cl * 8 + e;
      const int key = (kap & 51) | ((kap & 4) << 1) | ((kap & 8) >> 1); // swap bits 2,3
      h[e] = (_Float16)tile[key][d];
    }
    *(f16x8*)(dst + (size_t)c * 8) = h;
  }
}

// ---- Prepass C: mask int32 -> bits[b][row>>6][kv][row&63] u64 ----
__global__ __launch_bounds__(256)
void pack_mask(const int* __restrict__ M, u64* __restrict__ MB) {
  const int gid  = blockIdx.x * 256 + threadIdx.x;
  const int wv   = gid >> 6, lane = gid & 63;
  const int kv   = wv & (NKV - 1);
  const int row  = (wv >> 5) & (Sc - 1);
  const int b    = wv >> 16;
  const int m    = M[((size_t)b * Sc + row) * Sc + (size_t)kv * 64 + lane];
  const u64 bits = __ballot(m != 0);
  if (lane == 0)
    MB[(((size_t)b * NQ + (row >> 6)) * NKV + kv) * 64 + (row & 63)] = bits;
}

// ---- Main: 8 waves = 4 q-groups x 2 kt-halves; 32x32x16; epilogue O/l pair-reduce ----
// LDS (bytes): buf*16384 + {K:0 | V:8192} + kt/dt*4096 + (l&31)*128 + chunk*16
// chunk(s) = ((s<<1)|hb) ^ ((l&31)&7)
__global__ __launch_bounds__(512, 6)
void attn_fwd9(const float* __restrict__ Q, const _Float16* __restrict__ Ksw,
               const _Float16* __restrict__ Vsw, const u64* __restrict__ MB,
               float* __restrict__ O)
{
  // XCD-chunked swizzle: 1024 blocks = 8 XCDs x 128
  const int bid = (blockIdx.x & 7) * 128 + (blockIdx.x >> 3);
  const int qt  = bid & (NQT - 1);
  const int bh  = bid >> 4;
  const int b   = bh >> 4;
  const int q0  = qt * QB;

  const int tid = threadIdx.x;
  const int w   = tid >> 6;       // 0..7
  const int g   = w >> 1;         // q-group 0..3 (rows [32g, 32g+32))
  const int kt  = w & 1;          // key-half of each KV tile
  const int l   = tid & 63;
  const int q5  = l & 31;         // lane's q-row within the group
  const int hb  = l >> 5;         // 0/1
  const int xb  = q5 & 7;

  __shared__ _Float16 SB[16384 + 256];  // 32 KB staging (reused for epilogue O) + 512B l-exchange
  const char* sb = (const char*)SB;

  // per-lane ds_read byte offsets per k/kappa-step s
  int as_[4];
  #pragma unroll
  for (int s = 0; s < 4; ++s)
    as_[s] = q5 * 128 + (((((s << 1) | hb)) ^ xb) << 4);

  // Q B-operand: col=q=q5, k-slot of step s = s*16 + 8*hb + e (same for both kt)
  f16x8 qf[4];
  {
    const float qs = 0.125f * 1.4426950408889634f;
    const float* qr = Q + ((size_t)bh * Sc + q0 + g * 32 + q5) * Dc + 8 * hb;
    #pragma unroll
    for (int s = 0; s < 4; ++s) {
      const float4 f0 = *(const float4*)(qr + s * 16);
      const float4 f1 = *(const float4*)(qr + s * 16 + 4);
      f16x8 t = {(_Float16)(f0.x * qs), (_Float16)(f0.y * qs),
                 (_Float16)(f0.z * qs), (_Float16)(f0.w * qs),
                 (_Float16)(f1.x * qs), (_Float16)(f1.y * qs),
                 (_Float16)(f1.z * qs), (_Float16)(f1.w * qs)};
      qf[s] = t;
    }
  }

  f32x16 o0 = zero16(), o1 = zero16();    // partial O over this wave's key-half
  float la = 0.f, lb_ = 0.f;              // two accumulators break the fdot2 chain
  const float NEGL = -1.4426950e9f;

  const char* KswT = (const char*)(Ksw + (size_t)bh * Sc * Dc);
  const char* VswT = (const char*)(Vsw + (size_t)bh * Sc * Dc);
  const int row = q0 + g * 32 + q5;
  const u64* Mb = MB + ((size_t)(b * NQ + (row >> 6)) * NKV) * 64 + (row & 63);

  // stage: wave w copies 2 KB of the 16 KB tile (K: waves 0-3, V: waves 4-7)
  auto stage = [&](int kvt, int buf) {
    const char* gp = (w < 4) ? KswT + (size_t)kvt * 8192 + w * 2048
                             : VswT + (size_t)kvt * 8192 + (w - 4) * 2048;
    char* lbp = (char*)SB + buf * 16384 + ((w < 4) ? w * 2048 : 8192 + (w - 4) * 2048);
    gload16(gp + l * 16, lbp);
    gload16(gp + 1024 + l * 16, lbp + 1024);
  };

  auto body = [&](int buf, u64 mbits) {
    const int base = buf * 16384;
    const int kbase = base + kt * 4096;
    // S^T (this kt only): acc[reg] = S[key = kt*32 + (reg&3)+8*(reg>>2)+4*hb][q=q5]
    f32x16 acc = zero16();
    __builtin_amdgcn_s_setprio(1);
    acc = mfma32(*(const f16x8*)(sb + kbase + as_[0]), qf[0], acc);
    acc = mfma32(*(const f16x8*)(sb + kbase + as_[1]), qf[1], acc);
    acc = mfma32(*(const f16x8*)(sb + kbase + as_[2]), qf[2], acc);
    acc = mfma32(*(const f16x8*)(sb + kbase + as_[3]), qf[3], acc);
    __builtin_amdgcn_s_setprio(0);

    // mask-select + exp2 + pack + l (constant-max softmax)
    const unsigned mh = (unsigned)(mbits >> (32 * kt));
    #pragma unroll
    for (int b2 = 0; b2 < 4; ++b2) {
      const unsigned nib = (mh >> (8 * b2 + 4 * hb)) & 0xFu;
      #pragma unroll
      for (int a2 = 0; a2 < 4; ++a2) {
        const int r = 4 * b2 + a2;
        acc[r] = fast_exp2(((nib >> a2) & 1u) ? acc[r] : NEGL);
      }
    }
    u32x4 pw0, pw1;     // PV A-words for kappa-steps sigma = 2kt (pw0), 2kt+1 (pw1)
    #pragma unroll
    for (int i = 0; i < 4; ++i) {
      pw0[i] = pkrtz(acc[2 * i], acc[2 * i + 1]);
      pw1[i] = pkrtz(acc[8 + 2 * i], acc[8 + 2 * i + 1]);
      la  = dot2acc(pw0[i], la);
      lb_ = dot2acc(pw1[i], lb_);
    }
    const f16x8 pa0 = __builtin_bit_cast(f16x8, pw0);
    const f16x8 pa1 = __builtin_bit_cast(f16x8, pw1);

    // O += P V over this key-half: sigma = 2kt+j, dt = 0/1
    const int s0 = 2 * kt, s1 = 2 * kt + 1;
    __builtin_amdgcn_s_setprio(1);
    o0 = mfma32(pa0, *(const f16x8*)(sb + base + 8192 + as_[s0]), o0);
    o0 = mfma32(pa1, *(const f16x8*)(sb + base + 8192 + as_[s1]), o0);
    o1 = mfma32(pa0, *(const f16x8*)(sb + base + 12288 + as_[s0]), o1);
    o1 = mfma32(pa1, *(const f16x8*)(sb + base + 12288 + as_[s1]), o1);
    __builtin_amdgcn_s_setprio(0);
  };

  // ---- 2-phase pipeline, statically double-buffered, mask prefetched ----
  u64 mb_next = Mb[0];
  stage(0, 0);
  __syncthreads();
  for (int kv = 0; kv < NKV; kv += 2) {
    const u64 mb0 = mb_next;
    const u64 mb1 = Mb[(size_t)(kv + 1) * 64];
    stage(kv + 1, 1);
    body(0, mb0);
    __syncthreads();
    if (kv + 2 < NKV) {
      mb_next = Mb[(size_t)(kv + 2) * 64];
      stage(kv + 2, 0);
    }
    body(1, mb1);
    __syncthreads();
  }

  // ---- epilogue: pair-reduce (kt=1 -> kt=0) via LDS, then O /= l ----
  float lsum = la + lb_;
  lsum += __shfl_xor(lsum, 32, 64);       // sum hb halves (disjoint keys)

  float* xch = (float*)SB;                // 32 KB: [g][lane][32 floats]
  float* lx  = (float*)(SB + 16384);      // 4 groups x 32 floats
  __syncthreads();                        // all bodies done before overwriting SB
  if (kt == 1) {
    float* dst = xch + ((g * 64 + l) << 5);
    #pragma unroll
    for (int i = 0; i < 4; ++i) {
      *(float4*)(dst + 4 * i)      = float4{o0[4*i], o0[4*i+1], o0[4*i+2], o0[4*i+3]};
      *(float4*)(dst + 16 + 4 * i) = float4{o1[4*i], o1[4*i+1], o1[4*i+2], o1[4*i+3]};
    }
    if (hb == 0) lx[g * 32 + q5] = lsum;
  }
  __syncthreads();
  if (kt == 0) {
    const float* src = xch + ((g * 64 + l) << 5);
    #pragma unroll
    for (int i = 0; i < 16; ++i) { o0[i] += src[i]; o1[i] += src[16 + i]; }
    const float lt = lsum + lx[g * 32 + q5];
    #pragma unroll
    for (int reg = 0; reg < 16; ++reg) {
      const int qrow = (reg & 3) + 8 * (reg >> 2) + 4 * hb;
      const float li = 1.0f / __shfl(lt, qrow, 64);
      float* op = O + ((size_t)bh * Sc + q0 + g * 32 + qrow) * Dc + q5;
      op[0]  = o0[reg] * li;
      op[32] = o1[reg] * li;
    }
  }
}

// ---------------- Fallback (round-1 kernel, used if ws too small) ----------------
constexpr int LDSW = KVBLK + 8;

__global__ __launch_bounds__(256)
void attn_fwd_v1(const float* __restrict__ Q, const float* __restrict__ K,
                 const float* __restrict__ V, const int* __restrict__ M,
                 float* __restrict__ O)
{
  const int bid   = blockIdx.x;
  const int qtile = bid & 31;
  const int bh    = bid >> 5;
  const int b     = bh >> 4;

  const float* Qp = Q + ((size_t)bh * Sc + (size_t)qtile * 64) * Dc;
  const float* Kp = K + (size_t)bh * Sc * Dc;
  const float* Vp = V + (size_t)bh * Sc * Dc;
  const int*   Mp = M + (size_t)b * Sc * Sc + (size_t)qtile * 64 * Sc;
  float*       Op = O + ((size_t)bh * Sc + (size_t)qtile * 64) * Dc;

  __shared__ _Float16 Klds [KVBLK][LDSW];
  __shared__ _Float16 Vtlds[Dc]   [LDSW];
  __shared__ _Float16 Pl   [64]   [LDSW];

  const int tid = threadIdx.x;
  const int w   = tid >> 6;
  const int l   = tid & 63;
  const int lg  = l >> 4;
  const int lc  = l & 15;

  f16x8 qf[2];
  {
    const float qs = 0.125f * 1.4426950408889634f;
    const float* qrow = Qp + (size_t)(w * 16 + lc) * Dc + 8 * lg;
    #pragma unroll
    for (int ks = 0; ks < 2; ++ks) {
      f16x8 t;
      #pragma unroll
      for (int e = 0; e < 8; ++e) t[e] = (_Float16)(qrow[ks * 32 + e] * qs);
      qf[ks] = t;
    }
  }

  f32x4 o_acc[4];
  #pragma unroll
  for (int nt = 0; nt < 4; ++nt) o_acc[nt] = (f32x4){0.f, 0.f, 0.f, 0.f};
  float m_r[4], l_r[4];
  #pragma unroll
  for (int r = 0; r < 4; ++r) { m_r[r] = -3.0e38f; l_r[r] = 0.f; }
  const float NEGL = -1.4426950e9f;

  for (int kv = 0; kv < NKV; ++kv) {
    const float* Kt = Kp + (size_t)kv * KVBLK * Dc;
    const float* Vt = Vp + (size_t)kv * KVBLK * Dc;
    __syncthreads();
    {
      const int r = tid >> 2, c0 = (tid & 3) * 16;
      const float* src = Kt + (size_t)r * Dc + c0;
      f16x8 h0, h1;
      #pragma unroll
      for (int e = 0; e < 8; ++e) h0[e] = (_Float16)src[e];
      #pragma unroll
      for (int e = 0; e < 8; ++e) h1[e] = (_Float16)src[8 + e];
      *(f16x8*)&Klds[r][c0]     = h0;
      *(f16x8*)&Klds[r][c0 + 8] = h1;
    }
    {
      const int r0 = (tid >> 4) * 4, c0 = (tid & 15) * 4;
      float a_[4][4];
      #pragma unroll
      for (int i = 0; i < 4; ++i) {
        const float4 v4 = *(const float4*)(Vt + (size_t)(r0 + i) * Dc + c0);
        a_[i][0] = v4.x; a_[i][1] = v4.y; a_[i][2] = v4.z; a_[i][3] = v4.w;
      }
      #pragma unroll
      for (int j = 0; j < 4; ++j) {
        f16x4 t = {(_Float16)a_[0][j], (_Float16)a_[1][j],
                   (_Float16)a_[2][j], (_Float16)a_[3][j]};
        *(f16x4*)&Vtlds[c0 + j][r0] = t;
      }
    }
    __syncthreads();

    f32x4 s_acc[4];
    #pragma unroll
    for (int nt = 0; nt < 4; ++nt) {
      f32x4 acc = (f32x4){0.f, 0.f, 0.f, 0.f};
      #pragma unroll
      for (int ks = 0; ks < 2; ++ks) {
        f16x8 kf = *(const f16x8*)&Klds[nt * 16 + lc][ks * 32 + 8 * lg];
        acc = __builtin_amdgcn_mfma_f32_16x16x32_f16(qf[ks], kf, acc, 0, 0, 0);
      }
      s_acc[nt] = acc;
    }

    const int* mbase = Mp + (size_t)kv * KVBLK + lc;
    #pragma unroll
    for (int r = 0; r < 4; ++r) {
      const int qrow = w * 16 + 4 * lg + r;
      const int* mr = mbase + (size_t)qrow * Sc;
      float s0 = (mr[0]  != 0) ? s_acc[0][r] : NEGL;
      float s1 = (mr[16] != 0) ? s_acc[1][r] : NEGL;
      float s2 = (mr[32] != 0) ? s_acc[2][r] : NEGL;
      float s3 = (mr[48] != 0) ? s_acc[3][r] : NEGL;
      float mx = fmaxf(fmaxf(s0, s1), fmaxf(s2, s3));
      #pragma unroll
      for (int off = 1; off < 16; off <<= 1)
        mx = fmaxf(mx, __shfl_xor(mx, off, 64));
      const float mn   = fmaxf(m_r[r], mx);
      const float corr = fast_exp2(m_r[r] - mn);
      m_r[r] = mn;
      float p0 = fast_exp2(s0 - mn);
      float p1 = fast_exp2(s1 - mn);
      float p2 = fast_exp2(s2 - mn);
      float p3 = fast_exp2(s3 - mn);
      float rs = (p0 + p1) + (p2 + p3);
      #pragma unroll
      for (int off = 1; off < 16; off <<= 1)
        rs += __shfl_xor(rs, off, 64);
      l_r[r] = l_r[r] * corr + rs;
      #pragma unroll
      for (int nt = 0; nt < 4; ++nt) o_acc[nt][r] *= corr;
      Pl[qrow][lc]      = (_Float16)p0;
      Pl[qrow][16 + lc] = (_Float16)p1;
      Pl[qrow][32 + lc] = (_Float16)p2;
      Pl[qrow][48 + lc] = (_Float16)p3;
    }

    #pragma unroll
    for (int nt = 0; nt < 4; ++nt) {
      #pragma unroll
      for (int ks = 0; ks < 2; ++ks) {
        f16x8 pf = *(const f16x8*)&Pl[w * 16 + lc][ks * 32 + 8 * lg];
        f16x8 vf = *(const f16x8*)&Vtlds[nt * 16 + lc][ks * 32 + 8 * lg];
        o_acc[nt] = __builtin_amdgcn_mfma_f32_16x16x32_f16(pf, vf, o_acc[nt], 0, 0, 0);
      }
    }
  }

  #pragma unroll
  for (int r = 0; r < 4; ++r) {
    const float inv = 1.0f / l_r[r];
    float* orow = Op + (size_t)(w * 16 + 4 * lg + r) * Dc;
    #pragma unroll
    for (int nt = 0; nt < 4; ++nt)
      orow[nt * 16 + lc] = o_acc[nt][r] * inv;
  }
}

extern "C" void kernel_launch(void* const* d_in, const int* in_sizes, int n_in,
                              void* d_out, int out_size, void* d_ws, size_t ws_size,
                              hipStream_t stream) {
  (void)in_sizes; (void)n_in; (void)out_size;
  const float* Q = (const float*)d_in[0];
  const float* K = (const float*)d_in[1];
  const float* V = (const float*)d_in[2];
  const int*   M = (const int*)d_in[3];
  float*       O = (float*)d_out;

  const size_t nKV      = (size_t)Bc * Hc * Sc * Dc;        // 8,388,608
  const size_t bytesK16 = nKV * 2;                           // 16 MiB
  const size_t bytesMB  = (size_t)Bc * NQ * NKV * 64 * 8;    // 2 MiB
  const size_t need     = 2 * bytesK16 + bytesMB;

  if (ws_size >= need) {
    _Float16* K16  = (_Float16*)d_ws;
    _Float16* Vt16 = (_Float16*)((char*)d_ws + bytesK16);
    u64*      MBp  = (u64*)((char*)d_ws + 2 * bytesK16);
    hipLaunchKernelGGL(cvt_k_sw,   dim3(2048),  dim3(256), 0, stream, K, K16);
    hipLaunchKernelGGL(cvt_v_sw2,  dim3(2048),  dim3(256), 0, stream, V, Vt16);
    hipLaunchKernelGGL(pack_mask,  dim3(65536), dim3(256), 0, stream, M, MBp);
    hipLaunchKernelGGL(attn_fwd9,  dim3(1024),  dim3(512), 0, stream, Q, K16, Vt16, MBp, O);
  } else {
    hipLaunchKernelGGL(attn_fwd_v1, dim3(2048), dim3(256), 0, stream, Q, K, V, M, O);
  }
}

// Round 12
// 220.119 us; speedup vs baseline: 1.4357x; 1.4357x over previous
//
#include <hip/hip_runtime.h>

typedef _Float16 f16x8 __attribute__((ext_vector_type(8)));
typedef _Float16 f16x4 __attribute__((ext_vector_type(4)));
typedef _Float16 f16x2 __attribute__((ext_vector_type(2)));
typedef float    f32x4 __attribute__((ext_vector_type(4)));
typedef float    f32x16 __attribute__((ext_vector_type(16)));
typedef unsigned u32x4 __attribute__((ext_vector_type(4)));
typedef unsigned long long u64;

constexpr int Bc = 4, Hc = 16, Sc = 2048, Dc = 64;
constexpr int KVBLK = 64;
constexpr int NKV = Sc / KVBLK;   // 32 kv tiles (64 keys); 64 half-tile bodies
constexpr int QB  = 128;          // q rows per block (4 waves x 32)
constexpr int NQT = Sc / QB;      // 16
constexpr int NQ  = 32;           // mask row-block granularity (64 rows)

__device__ __forceinline__ float fast_exp2(float x) {
#if __has_builtin(__builtin_amdgcn_exp2f)
  return __builtin_amdgcn_exp2f(x);
#else
  return exp2f(x);
#endif
}

__device__ __forceinline__ f32x16 mfma32(f16x8 a, f16x8 b, f32x16 c) {
  return __builtin_amdgcn_mfma_f32_32x32x16_f16(a, b, c, 0, 0, 0);
}

__device__ __forceinline__ unsigned pkrtz(float x, float y) {
  return __builtin_bit_cast(unsigned, __builtin_amdgcn_cvt_pkrtz(x, y));
}

__device__ __forceinline__ float dot2acc(unsigned pk, float acc) {
#if __has_builtin(__builtin_amdgcn_fdot2)
  const f16x2 one2 = {(_Float16)1.f, (_Float16)1.f};
  return __builtin_amdgcn_fdot2(__builtin_bit_cast(f16x2, pk), one2, acc, false);
#else
  const f16x2 v = __builtin_bit_cast(f16x2, pk);
  return acc + (float)v[0] + (float)v[1];
#endif
}

__device__ __forceinline__ f32x16 zero16() {
  f32x16 z;
  #pragma unroll
  for (int i = 0; i < 16; ++i) z[i] = 0.f;
  return z;
}

// ---- Prepass A: K fp32 [bh][key][d] -> fp16 FRAGMENT-LINEAR ----
// chunk c of tile (16B): kt=c>>8, s=(c>>6)&3, l=c&63
// holds K[kt*32 + (l&31)][s*16 + 8*(l>>5) .. +8]  (QK A-operand for lane l, step s)
__global__ __launch_bounds__(256)
void cvt_k_fr(const float* __restrict__ K, _Float16* __restrict__ Ko) {
  const int tile = blockIdx.x;              // bh*32 + kvt
  const int t = threadIdx.x;
  const float* src = K + (size_t)tile * 4096;
  _Float16* dst = Ko + (size_t)tile * 4096;
  #pragma unroll
  for (int cc = 0; cc < 2; ++cc) {
    const int c = t + cc * 256;
    const int kt = c >> 8, s = (c >> 6) & 3, l = c & 63;
    const int key = kt * 32 + (l & 31);
    const int d0  = s * 16 + 8 * (l >> 5);
    const float* p = src + key * 64 + d0;
    const float4 a  = *(const float4*)p;
    const float4 b2 = *(const float4*)(p + 4);
    f16x8 h = {(_Float16)a.x, (_Float16)a.y, (_Float16)a.z, (_Float16)a.w,
               (_Float16)b2.x, (_Float16)b2.y, (_Float16)b2.z, (_Float16)b2.w};
    *(f16x8*)(dst + (size_t)c * 8) = h;
  }
}

// ---- Prepass B: V fp32 [bh][key][d] -> fp16 FRAGMENT-LINEAR transposed+permuted ----
// chunk c: dt=c>>8, sigma=(c>>6)&3, l=c&63
// holds V[bitswap23(sigma*16+8*(l>>5)+e)][dt*32 + (l&31)]  (PV B-operand)
__global__ __launch_bounds__(256)
void cvt_v_fr(const float* __restrict__ V, _Float16* __restrict__ Vo) {
  __shared__ float tile[64][65];            // [key][d]
  const int tb = blockIdx.x;                // bh*32 + kvt
  const int t = threadIdx.x;
  const float* src = V + (size_t)tb * 4096;
  {
    const int r = t >> 2, c0 = (t & 3) * 16;
    #pragma unroll
    for (int j = 0; j < 16; j += 4)
      *(float4*)&tile[r][c0 + j] = *(const float4*)(src + r * 64 + c0 + j);
  }
  __syncthreads();
  _Float16* dst = Vo + (size_t)tb * 4096;
  #pragma unroll
  for (int cc = 0; cc < 2; ++cc) {
    const int c = t + cc * 256;
    const int dt = c >> 8, sigma = (c >> 6) & 3, l = c & 63;
    const int d = dt * 32 + (l & 31);
    f16x8 h;
    #pragma unroll
    for (int e = 0; e < 8; ++e) {
      const int kap = sigma * 16 + 8 * (l >> 5) + e;
      const int key = (kap & 51) | ((kap & 4) << 1) | ((kap & 8) >> 1); // swap bits 2,3
      h[e] = (_Float16)tile[key][d];
    }
    *(f16x8*)(dst + (size_t)c * 8) = h;
  }
}

// ---- Prepass C: mask int32 -> bits[b][row>>6][kv][row&63] u64 ----
__global__ __launch_bounds__(256)
void pack_mask(const int* __restrict__ M, u64* __restrict__ MB) {
  const int gid  = blockIdx.x * 256 + threadIdx.x;
  const int wv   = gid >> 6, lane = gid & 63;
  const int kv   = wv & (NKV - 1);
  const int row  = (wv >> 5) & (Sc - 1);
  const int b    = wv >> 16;
  const int m    = M[((size_t)b * Sc + row) * Sc + (size_t)kv * 64 + lane];
  const u64 bits = __ballot(m != 0);
  if (lane == 0)
    MB[(((size_t)b * NQ + (row >> 6)) * NKV + kv) * 64 + (row & 63)] = bits;
}

// ---- Main: barrier-free, LDS-free; 4 independent waves x 32q; 64 half-tile bodies ----
__global__ __launch_bounds__(256, 4)
void attn_fwd10(const float* __restrict__ Q, const _Float16* __restrict__ Kf,
                const _Float16* __restrict__ Vf, const u64* __restrict__ MB,
                float* __restrict__ O)
{
  // XCD-chunked swizzle: 1024 blocks = 8 XCDs x 128
  const int bid = (blockIdx.x & 7) * 128 + (blockIdx.x >> 3);
  const int qt  = bid & (NQT - 1);
  const int bh  = bid >> 4;
  const int b   = bh >> 4;
  const int q0  = qt * QB;

  const int tid = threadIdx.x;
  const int g   = tid >> 6;       // wave 0..3 owns q rows [32g, 32g+32)
  const int l   = tid & 63;
  const int q5  = l & 31;
  const int hb  = l >> 5;

  // Q B-operand: col=q=q5, k of step s = s*16 + 8*hb + e; scale*log2e folded
  f16x8 qf[4];
  {
    const float qs = 0.125f * 1.4426950408889634f;
    const float* qr = Q + ((size_t)bh * Sc + q0 + g * 32 + q5) * Dc + 8 * hb;
    #pragma unroll
    for (int s = 0; s < 4; ++s) {
      const float4 f0 = *(const float4*)(qr + s * 16);
      const float4 f1 = *(const float4*)(qr + s * 16 + 4);
      f16x8 t = {(_Float16)(f0.x * qs), (_Float16)(f0.y * qs),
                 (_Float16)(f0.z * qs), (_Float16)(f0.w * qs),
                 (_Float16)(f1.x * qs), (_Float16)(f1.y * qs),
                 (_Float16)(f1.z * qs), (_Float16)(f1.w * qs)};
      qf[s] = t;
    }
  }

  f32x16 o0 = zero16(), o1 = zero16();
  float la = 0.f, lb_ = 0.f;
  const float NEGL = -1.4426950e9f;   // exp2 -> exact 0 for masked keys

  const char* Kb = (const char*)(Kf + (size_t)bh * Sc * Dc);
  const char* Vb = (const char*)(Vf + (size_t)bh * Sc * Dc);
  const int row = q0 + g * 32 + q5;
  const unsigned* Mb32 =
      (const unsigned*)(MB + ((size_t)(b * NQ + (row >> 6)) * NKV) * 64 + (row & 63));
  // u32 index for body (2*kv+kt): kv*128 + kt  (low word = keys 0..31)

  // body = 2*kv + kt; K frags at Kb + body*4096 + {0,1024,2048,3072} + l*16
  auto loadK = [&](int body, f16x8* kr) {
    const char* p = Kb + (size_t)body * 4096 + l * 16;
    kr[0] = *(const f16x8*)(p);
    kr[1] = *(const f16x8*)(p + 1024);
    kr[2] = *(const f16x8*)(p + 2048);
    kr[3] = *(const f16x8*)(p + 3072);
  };
  // V frags: sigma = 2kt+j, dt = 0/1:  Vb + kv*8192 + dt*4096 + sigma*1024 + l*16
  auto loadV = [&](int body, f16x8* vr) {
    const char* p = Vb + (size_t)(body >> 1) * 8192 + (size_t)(body & 1) * 2048 + l * 16;
    vr[0] = *(const f16x8*)(p);               // dt0, sigma 2kt
    vr[1] = *(const f16x8*)(p + 1024);        // dt0, sigma 2kt+1
    vr[2] = *(const f16x8*)(p + 4096);        // dt1, sigma 2kt
    vr[3] = *(const f16x8*)(p + 5120);        // dt1, sigma 2kt+1
  };

  auto compute = [&](const f16x8* kr, const f16x8* vr, unsigned mh) {
    // S^T: acc[reg] = S[key = kt*32 + (reg&3)+8*(reg>>2)+4*hb][q=q5]
    f32x16 acc = zero16();
    __builtin_amdgcn_s_setprio(1);
    acc = mfma32(kr[0], qf[0], acc);
    acc = mfma32(kr[1], qf[1], acc);
    acc = mfma32(kr[2], qf[2], acc);
    acc = mfma32(kr[3], qf[3], acc);
    __builtin_amdgcn_s_setprio(0);
    // constant-max softmax: pe = exp2(mask ? s : NEGL)
    #pragma unroll
    for (int b2 = 0; b2 < 4; ++b2) {
      const unsigned nib = (mh >> (8 * b2 + 4 * hb)) & 0xFu;
      #pragma unroll
      for (int a2 = 0; a2 < 4; ++a2) {
        const int r = 4 * b2 + a2;
        acc[r] = fast_exp2(((nib >> a2) & 1u) ? acc[r] : NEGL);
      }
    }
    // pack into PV A-fragments (bitswap23-matched V: register-direct) + l via fdot2
    u32x4 pw0, pw1;
    #pragma unroll
    for (int i = 0; i < 4; ++i) {
      pw0[i] = pkrtz(acc[2 * i], acc[2 * i + 1]);
      pw1[i] = pkrtz(acc[8 + 2 * i], acc[8 + 2 * i + 1]);
      la  = dot2acc(pw0[i], la);
      lb_ = dot2acc(pw1[i], lb_);
    }
    const f16x8 pa0 = __builtin_bit_cast(f16x8, pw0);
    const f16x8 pa1 = __builtin_bit_cast(f16x8, pw1);
    __builtin_amdgcn_s_setprio(1);
    o0 = mfma32(pa0, vr[0], o0);
    o0 = mfma32(pa1, vr[1], o0);
    o1 = mfma32(pa0, vr[2], o1);
    o1 = mfma32(pa1, vr[3], o1);
    __builtin_amdgcn_s_setprio(0);
  };

  // ---- free-running pipeline, depth 1, static A/B reg buffers (unroll 2) ----
  f16x8 kA[4], vA[4], kB[4], vB[4];
  unsigned mA = Mb32[0];
  loadK(0, kA);
  loadV(0, vA);
  for (int body = 0; body < 2 * NKV; body += 2) {
    const int n1 = body + 1;
    const unsigned mB = Mb32[(n1 >> 1) * 128 + (n1 & 1)];
    loadK(n1, kB);
    loadV(n1, vB);
    compute(kA, vA, mA);
    if (body + 2 < 2 * NKV) {
      const int n2 = body + 2;
      mA = Mb32[(n2 >> 1) * 128 + (n2 & 1)];
      loadK(n2, kA);
      loadV(n2, vA);
    }
    compute(kB, vB, mB);
  }

  // ---- epilogue: l over both hb key-halves, O /= l ----
  float lt = la + lb_;
  lt += __shfl_xor(lt, 32, 64);
  #pragma unroll
  for (int reg = 0; reg < 16; ++reg) {
    const int qrow = (reg & 3) + 8 * (reg >> 2) + 4 * hb;
    const float li = 1.0f / __shfl(lt, qrow, 64);
    float* op = O + ((size_t)bh * Sc + q0 + g * 32 + qrow) * Dc + q5;
    op[0]  = o0[reg] * li;
    op[32] = o1[reg] * li;
  }
}

// ---------------- Fallback (round-1 kernel, used if ws too small) ----------------
constexpr int LDSW = KVBLK + 8;

__global__ __launch_bounds__(256)
void attn_fwd_v1(const float* __restrict__ Q, const float* __restrict__ K,
                 const float* __restrict__ V, const int* __restrict__ M,
                 float* __restrict__ O)
{
  const int bid   = blockIdx.x;
  const int qtile = bid & 31;
  const int bh    = bid >> 5;
  const int b     = bh >> 4;

  const float* Qp = Q + ((size_t)bh * Sc + (size_t)qtile * 64) * Dc;
  const float* Kp = K + (size_t)bh * Sc * Dc;
  const float* Vp = V + (size_t)bh * Sc * Dc;
  const int*   Mp = M + (size_t)b * Sc * Sc + (size_t)qtile * 64 * Sc;
  float*       Op = O + ((size_t)bh * Sc + (size_t)qtile * 64) * Dc;

  __shared__ _Float16 Klds [KVBLK][LDSW];
  __shared__ _Float16 Vtlds[Dc]   [LDSW];
  __shared__ _Float16 Pl   [64]   [LDSW];

  const int tid = threadIdx.x;
  const int w   = tid >> 6;
  const int l   = tid & 63;
  const int lg  = l >> 4;
  const int lc  = l & 15;

  f16x8 qf[2];
  {
    const float qs = 0.125f * 1.4426950408889634f;
    const float* qrow = Qp + (size_t)(w * 16 + lc) * Dc + 8 * lg;
    #pragma unroll
    for (int ks = 0; ks < 2; ++ks) {
      f16x8 t;
      #pragma unroll
      for (int e = 0; e < 8; ++e) t[e] = (_Float16)(qrow[ks * 32 + e] * qs);
      qf[ks] = t;
    }
  }

  f32x4 o_acc[4];
  #pragma unroll
  for (int nt = 0; nt < 4; ++nt) o_acc[nt] = (f32x4){0.f, 0.f, 0.f, 0.f};
  float m_r[4], l_r[4];
  #pragma unroll
  for (int r = 0; r < 4; ++r) { m_r[r] = -3.0e38f; l_r[r] = 0.f; }
  const float NEGL = -1.4426950e9f;

  for (int kv = 0; kv < NKV; ++kv) {
    const float* Kt = Kp + (size_t)kv * KVBLK * Dc;
    const float* Vt = Vp + (size_t)kv * KVBLK * Dc;
    __syncthreads();
    {
      const int r = tid >> 2, c0 = (tid & 3) * 16;
      const float* src = Kt + (size_t)r * Dc + c0;
      f16x8 h0, h1;
      #pragma unroll
      for (int e = 0; e < 8; ++e) h0[e] = (_Float16)src[e];
      #pragma unroll
      for (int e = 0; e < 8; ++e) h1[e] = (_Float16)src[8 + e];
      *(f16x8*)&Klds[r][c0]     = h0;
      *(f16x8*)&Klds[r][c0 + 8] = h1;
    }
    {
      const int r0 = (tid >> 4) * 4, c0 = (tid & 15) * 4;
      float a_[4][4];
      #pragma unroll
      for (int i = 0; i < 4; ++i) {
        const float4 v4 = *(const float4*)(Vt + (size_t)(r0 + i) * Dc + c0);
        a_[i][0] = v4.x; a_[i][1] = v4.y; a_[i][2] = v4.z; a_[i][3] = v4.w;
      }
      #pragma unroll
      for (int j = 0; j < 4; ++j) {
        f16x4 t = {(_Float16)a_[0][j], (_Float16)a_[1][j],
                   (_Float16)a_[2][j], (_Float16)a_[3][j]};
        *(f16x4*)&Vtlds[c0 + j][r0] = t;
      }
    }
    __syncthreads();

    f32x4 s_acc[4];
    #pragma unroll
    for (int nt = 0; nt < 4; ++nt) {
      f32x4 acc = (f32x4){0.f, 0.f, 0.f, 0.f};
      #pragma unroll
      for (int ks = 0; ks < 2; ++ks) {
        f16x8 kf = *(const f16x8*)&Klds[nt * 16 + lc][ks * 32 + 8 * lg];
        acc = __builtin_amdgcn_mfma_f32_16x16x32_f16(qf[ks], kf, acc, 0, 0, 0);
      }
      s_acc[nt] = acc;
    }

    const int* mbase = Mp + (size_t)kv * KVBLK + lc;
    #pragma unroll
    for (int r = 0; r < 4; ++r) {
      const int qrow = w * 16 + 4 * lg + r;
      const int* mr = mbase + (size_t)qrow * Sc;
      float s0 = (mr[0]  != 0) ? s_acc[0][r] : NEGL;
      float s1 = (mr[16] != 0) ? s_acc[1][r] : NEGL;
      float s2 = (mr[32] != 0) ? s_acc[2][r] : NEGL;
      float s3 = (mr[48] != 0) ? s_acc[3][r] : NEGL;
      float mx = fmaxf(fmaxf(s0, s1), fmaxf(s2, s3));
      #pragma unroll
      for (int off = 1; off < 16; off <<= 1)
        mx = fmaxf(mx, __shfl_xor(mx, off, 64));
      const float mn   = fmaxf(m_r[r], mx);
      const float corr = fast_exp2(m_r[r] - mn);
      m_r[r] = mn;
      float p0 = fast_exp2(s0 - mn);
      float p1 = fast_exp2(s1 - mn);
      float p2 = fast_exp2(s2 - mn);
      float p3 = fast_exp2(s3 - mn);
      float rs = (p0 + p1) + (p2 + p3);
      #pragma unroll
      for (int off = 1; off < 16; off <<= 1)
        rs += __shfl_xor(rs, off, 64);
      l_r[r] = l_r[r] * corr + rs;
      #pragma unroll
      for (int nt = 0; nt < 4; ++nt) o_acc[nt][r] *= corr;
      Pl[qrow][lc]      = (_Float16)p0;
      Pl[qrow][16 + lc] = (_Float16)p1;
      Pl[qrow][32 + lc] = (_Float16)p2;
      Pl[qrow][48 + lc] = (_Float16)p3;
    }

    #pragma unroll
    for (int nt = 0; nt < 4; ++nt) {
      #pragma unroll
      for (int ks = 0; ks < 2; ++ks) {
        f16x8 pf = *(const f16x8*)&Pl[w * 16 + lc][ks * 32 + 8 * lg];
        f16x8 vf = *(const f16x8*)&Vtlds[nt * 16 + lc][ks * 32 + 8 * lg];
        o_acc[nt] = __builtin_amdgcn_mfma_f32_16x16x32_f16(pf, vf, o_acc[nt], 0, 0, 0);
      }
    }
  }

  #pragma unroll
  for (int r = 0; r < 4; ++r) {
    const float inv = 1.0f / l_r[r];
    float* orow = Op + (size_t)(w * 16 + 4 * lg + r) * Dc;
    #pragma unroll
    for (int nt = 0; nt < 4; ++nt)
      orow[nt * 16 + lc] = o_acc[nt][r] * inv;
  }
}

extern "C" void kernel_launch(void* const* d_in, const int* in_sizes, int n_in,
                              void* d_out, int out_size, void* d_ws, size_t ws_size,
                              hipStream_t stream) {
  (void)in_sizes; (void)n_in; (void)out_size;
  const float* Q = (const float*)d_in[0];
  const float* K = (const float*)d_in[1];
  const float* V = (const float*)d_in[2];
  const int*   M = (const int*)d_in[3];
  float*       O = (float*)d_out;

  const size_t nKV      = (size_t)Bc * Hc * Sc * Dc;        // 8,388,608
  const size_t bytesK16 = nKV * 2;                           // 16 MiB
  const size_t bytesMB  = (size_t)Bc * NQ * NKV * 64 * 8;    // 2 MiB
  const size_t need     = 2 * bytesK16 + bytesMB;

  if (ws_size >= need) {
    _Float16* K16  = (_Float16*)d_ws;
    _Float16* Vt16 = (_Float16*)((char*)d_ws + bytesK16);
    u64*      MBp  = (u64*)((char*)d_ws + 2 * bytesK16);
    hipLaunchKernelGGL(cvt_k_fr,   dim3(2048),  dim3(256), 0, stream, K, K16);
    hipLaunchKernelGGL(cvt_v_fr,   dim3(2048),  dim3(256), 0, stream, V, Vt16);
    hipLaunchKernelGGL(pack_mask,  dim3(65536), dim3(256), 0, stream, M, MBp);
    hipLaunchKernelGGL(attn_fwd10, dim3(1024),  dim3(256), 0, stream, Q, K16, Vt16, MBp, O);
  } else {
    hipLaunchKernelGGL(attn_fwd_v1, dim3(2048), dim3(256), 0, stream, Q, K, V, M, O);
  }
}

// Round 13
// 129.713 us; speedup vs baseline: 2.4363x; 1.6970x over previous
//
#include <hip/hip_runtime.h>

typedef _Float16 f16x8 __attribute__((ext_vector_type(8)));
typedef _Float16 f16x4 __attribute__((ext_vector_type(4)));
typedef _Float16 f16x2 __attribute__((ext_vector_type(2)));
typedef float    f32x4 __attribute__((ext_vector_type(4)));
typedef unsigned u32x4 __attribute__((ext_vector_type(4)));
typedef unsigned long long u64;

constexpr int Bc = 4, Hc = 16, Sc = 2048, Dc = 64;
constexpr int KVBLK = 64;
constexpr int NKV = Sc / KVBLK;   // 32
constexpr int QB  = 256;          // q rows per block (8 waves x 32: 2 fragments/wave)
constexpr int NQT = Sc / QB;      // 8
constexpr int NQ  = 32;           // mask row-block granularity (64 rows)

__device__ __forceinline__ float fast_exp2(float x) {
#if __has_builtin(__builtin_amdgcn_exp2f)
  return __builtin_amdgcn_exp2f(x);
#else
  return exp2f(x);
#endif
}

__device__ __forceinline__ void gload16(const void* g, void* l) {
  __builtin_amdgcn_global_load_lds(
      (const __attribute__((address_space(1))) void*)g,
      (__attribute__((address_space(3))) void*)l, 16, 0, 0);
}

__device__ __forceinline__ f32x4 mfma16(f16x8 a, f16x8 b, f32x4 c) {
  return __builtin_amdgcn_mfma_f32_16x16x32_f16(a, b, c, 0, 0, 0);
}

__device__ __forceinline__ unsigned pkrtz(float x, float y) {
  return __builtin_bit_cast(unsigned, __builtin_amdgcn_cvt_pkrtz(x, y));
}

__device__ __forceinline__ float dot2acc(unsigned pk, float acc) {
#if __has_builtin(__builtin_amdgcn_fdot2)
  const f16x2 one2 = {(_Float16)1.f, (_Float16)1.f};
  return __builtin_amdgcn_fdot2(__builtin_bit_cast(f16x2, pk), one2, acc, false);
#else
  const f16x2 v = __builtin_bit_cast(f16x2, pk);
  return acc + (float)v[0] + (float)v[1];
#endif
}

// ---- Prepass A: K fp32 [bh][s][d] -> fp16 XOR-swizzled tiles ----
__global__ __launch_bounds__(256)
void cvt_k_sw(const float* __restrict__ K, _Float16* __restrict__ Ko) {
  const int tile = blockIdx.x;              // bh*32 + kvt
  const int t = threadIdx.x;
  const float* src = K + (size_t)tile * 4096;
  _Float16* dst = Ko + (size_t)tile * 4096;
  #pragma unroll
  for (int cc = 0; cc < 2; ++cc) {
    const int c = t + cc * 256;
    const int r = c >> 3, s = c & 7;
    const int ss = s ^ (r & 7);
    const float* p = src + r * 64 + ss * 8;
    const float4 a = *(const float4*)p;
    const float4 b2 = *(const float4*)(p + 4);
    f16x8 h = {(_Float16)a.x, (_Float16)a.y, (_Float16)a.z, (_Float16)a.w,
               (_Float16)b2.x, (_Float16)b2.y, (_Float16)b2.z, (_Float16)b2.w};
    *(f16x8*)(dst + (size_t)c * 8) = h;
  }
}

// ---- Prepass B: V -> fp16, transposed [d][key], keys PERMUTED by pi, XOR-swizzled ----
// pi(s): s = ks*32 + 8*lg + e  ->  key = 32*ks + 16*(e>>2) + 4*lg + (e&3)
__global__ __launch_bounds__(256)
void cvt_v_sw(const float* __restrict__ V, _Float16* __restrict__ Vo) {
  __shared__ float tile[64][65];            // [key][d]
  const int tb = blockIdx.x;                // bh*32 + kvt
  const int t = threadIdx.x;
  const float* src = V + (size_t)tb * 4096;
  {
    const int r = t >> 2, c0 = (t & 3) * 16;
    #pragma unroll
    for (int j = 0; j < 16; j += 4)
      *(float4*)&tile[r][c0 + j] = *(const float4*)(src + r * 64 + c0 + j);
  }
  __syncthreads();
  _Float16* dst = Vo + (size_t)tb * 4096;
  #pragma unroll
  for (int cc = 0; cc < 2; ++cc) {
    const int c = t + cc * 256;
    const int d = c >> 3, ss = c & 7;
    const int m = ss ^ (d & 7);             // logical chunk = ks*4+lg
    const int ks = m >> 2, lg = m & 3;
    f16x8 h;
    #pragma unroll
    for (int e = 0; e < 8; ++e) {
      const int key = 32 * ks + 16 * (e >> 2) + 4 * lg + (e & 3);
      h[e] = (_Float16)tile[key][d];
    }
    *(f16x8*)(dst + (size_t)c * 8) = h;
  }
}

// ---- Prepass C: mask int32 -> bits[b][row>>6][kv][row&63] u64 ----
__global__ __launch_bounds__(256)
void pack_mask(const int* __restrict__ M, u64* __restrict__ MB) {
  const int gid  = blockIdx.x * 256 + threadIdx.x;
  const int wv   = gid >> 6, lane = gid & 63;
  const int kv   = wv & (NKV - 1);
  const int row  = (wv >> 5) & (Sc - 1);
  const int b    = wv >> 16;
  const int m    = M[((size_t)b * Sc + row) * Sc + (size_t)kv * 64 + lane];
  const u64 bits = __ballot(m != 0);
  if (lane == 0)
    MB[(((size_t)b * NQ + (row >> 6)) * NKV + kv) * 64 + (row & 63)] = bits;
}

// ---- Main: QB=256, 8 waves x 32q (2 frags), counted-vmcnt pipeline, raw s_barrier ----
// LDS (bytes): buf*16384 + {K:0 | V:8192} + nt*2048 + lc*128 + slot*16
// slot(ks) = (ks*4 + lg) ^ (lc&7)
__global__ __launch_bounds__(512, 4)
void attn_fwd11(const float* __restrict__ Q, const _Float16* __restrict__ Ksw,
                const _Float16* __restrict__ Vsw, const u64* __restrict__ MB,
                float* __restrict__ O)
{
  // XCD-chunked swizzle: 512 blocks = 8 XCDs x 64
  const int bid = (blockIdx.x & 7) * 64 + (blockIdx.x >> 3);
  const int qt  = bid & (NQT - 1);
  const int bh  = bid >> 3;
  const int b   = bh >> 4;
  const int q0  = qt * QB;

  const int tid = threadIdx.x;
  const int w   = tid >> 6;    // 0..7 (wave owns q rows [32w, 32w+32))
  const int l   = tid & 63;
  const int lg  = l >> 4;      // 0..3
  const int lc  = l & 15;      // 0..15

  __shared__ _Float16 SB[16384];   // 32 KB: 2 bufs x (K 8KB | V 8KB)
  const char* sb = (const char*)SB;

  const int a0 = lc * 128 + (((0 + lg) ^ (lc & 7)) << 4);
  const int a1 = lc * 128 + (((4 + lg) ^ (lc & 7)) << 4);

  // Q fragments (B operand), 2 per wave: col=q=16*qa+lc, k=ks*32+8*lg+e
  f16x8 qf[2][2];
  {
    const float qs = 0.125f * 1.4426950408889634f;
    #pragma unroll
    for (int qa = 0; qa < 2; ++qa) {
      const float* qr = Q + ((size_t)bh * Sc + q0 + w * 32 + qa * 16 + lc) * Dc + 8 * lg;
      #pragma unroll
      for (int ks = 0; ks < 2; ++ks) {
        f16x8 t;
        #pragma unroll
        for (int e = 0; e < 8; ++e) t[e] = (_Float16)(qr[ks * 32 + e] * qs);
        qf[qa][ks] = t;
      }
    }
  }

  f32x4 o_acc[2][4];
  #pragma unroll
  for (int qa = 0; qa < 2; ++qa)
    #pragma unroll
    for (int nt = 0; nt < 4; ++nt) o_acc[qa][nt] = (f32x4){0.f, 0.f, 0.f, 0.f};
  float l_acc0 = 0.f, l_acc1 = 0.f;
  const float NEGL = -1.4426950e9f;   // exp2 -> exact 0 for masked keys

  const char* KswT = (const char*)(Ksw + (size_t)bh * Sc * Dc);
  const char* VswT = (const char*)(Vsw + (size_t)bh * Sc * Dc);
  const int row0 = q0 + w * 32 + lc;
  const int row1 = row0 + 16;
  const u64* Mb0 = MB + ((size_t)(b * NQ + (row0 >> 6)) * NKV) * 64 + (row0 & 63);
  const u64* Mb1 = MB + ((size_t)(b * NQ + (row1 >> 6)) * NKV) * 64 + (row1 & 63);

  // stage: wave w copies 2 KB of the 16 KB tile into buffer `buf` (2 gload16)
  auto stage = [&](int kvt, int buf) {
    const char* g = (w < 4) ? KswT + (size_t)kvt * 8192 + w * 2048
                            : VswT + (size_t)kvt * 8192 + (w - 4) * 2048;
    char* lb = (char*)SB + buf * 16384 + ((w < 4) ? w * 2048 : 8192 + (w - 4) * 2048);
    gload16(g + l * 16, lb);
    gload16(g + 1024 + l * 16, lb + 1024);
  };

  auto body = [&](int buf, u64 m0, u64 m1) {
    const int base = buf * 16384;
    // S^T = K Q^T for both q-fragments; K read once per nt
    f32x4 p[2][4];
    __builtin_amdgcn_s_setprio(1);
    #pragma unroll
    for (int nt = 0; nt < 4; ++nt) {
      const f16x8 k0 = *(const f16x8*)(sb + base + nt * 2048 + a0);
      const f16x8 k1 = *(const f16x8*)(sb + base + nt * 2048 + a1);
      #pragma unroll
      for (int qa = 0; qa < 2; ++qa) {
        f32x4 acc = (f32x4){0.f, 0.f, 0.f, 0.f};
        acc = mfma16(k0, qf[qa][0], acc);
        acc = mfma16(k1, qf[qa][1], acc);
        p[qa][nt] = acc;
      }
    }
    __builtin_amdgcn_s_setprio(0);
    // constant-max softmax: pe = exp2(mask ? s : NEGL)
    #pragma unroll
    for (int qa = 0; qa < 2; ++qa) {
      const u64 mbits = qa ? m1 : m0;
      #pragma unroll
      for (int nt = 0; nt < 4; ++nt) {
        const unsigned b4 = ((unsigned)(mbits >> (nt * 16 + 4 * lg))) & 0xFu;
        #pragma unroll
        for (int r = 0; r < 4; ++r)
          p[qa][nt][r] = fast_exp2(((b4 >> r) & 1u) ? p[qa][nt][r] : NEGL);
      }
    }
    // pack into PV A-fragments (pi-matched V) + l via fdot2
    f16x8 pa0[2], pa1[2];
    #pragma unroll
    for (int qa = 0; qa < 2; ++qa) {
      u32x4 u0, u1;
      #pragma unroll
      for (int i = 0; i < 4; ++i) {
        u0[i] = pkrtz(p[qa][i >> 1][(i & 1) * 2], p[qa][i >> 1][(i & 1) * 2 + 1]);
        u1[i] = pkrtz(p[qa][2 + (i >> 1)][(i & 1) * 2], p[qa][2 + (i >> 1)][(i & 1) * 2 + 1]);
      }
      float la = qa ? l_acc1 : l_acc0;
      #pragma unroll
      for (int i = 0; i < 4; ++i) { la = dot2acc(u0[i], la); la = dot2acc(u1[i], la); }
      if (qa) l_acc1 = la; else l_acc0 = la;
      pa0[qa] = __builtin_bit_cast(f16x8, u0);
      pa1[qa] = __builtin_bit_cast(f16x8, u1);
    }
    // O += P V : V read once per nt, shared by both fragments
    __builtin_amdgcn_s_setprio(1);
    #pragma unroll
    for (int nt = 0; nt < 4; ++nt) {
      const f16x8 v0 = *(const f16x8*)(sb + base + 8192 + nt * 2048 + a0);
      const f16x8 v1 = *(const f16x8*)(sb + base + 8192 + nt * 2048 + a1);
      o_acc[0][nt] = mfma16(pa0[0], v0, o_acc[0][nt]);
      o_acc[0][nt] = mfma16(pa1[0], v1, o_acc[0][nt]);
      o_acc[1][nt] = mfma16(pa0[1], v0, o_acc[1][nt]);
      o_acc[1][nt] = mfma16(pa1[1], v1, o_acc[1][nt]);
    }
    __builtin_amdgcn_s_setprio(0);
  };

  // ---- counted-vmcnt 2-buffer pipeline (per-iteration vmem = 2 gload + 2 mask = 4) ----
  u64 mA0 = Mb0[0], mA1 = Mb1[0];
  stage(0, 0);
  asm volatile("s_waitcnt vmcnt(0)" ::: "memory");
  __builtin_amdgcn_sched_barrier(0);
  __builtin_amdgcn_s_barrier();

  u64 mB0, mB1;
  for (int t = 0; t < NKV; t += 2) {
    // --- prefetch tile t+1 into B1, then run body(t) on B0 ---
    stage(t + 1, 1);
    mB0 = Mb0[(size_t)(t + 1) * 64];
    mB1 = Mb1[(size_t)(t + 1) * 64];
    asm volatile("s_waitcnt vmcnt(4)" ::: "memory");  // all but stage(t+1)+masks done
    __builtin_amdgcn_sched_barrier(0);
    __builtin_amdgcn_s_barrier();                      // B0 ready for all waves
    body(0, mA0, mA1);
    __builtin_amdgcn_s_barrier();                      // B0 readers done (WAR for stage(t+2))

    // --- prefetch tile t+2 into B0, then run body(t+1) on B1 ---
    if (t + 2 < NKV) {
      stage(t + 2, 0);
      mA0 = Mb0[(size_t)(t + 2) * 64];
      mA1 = Mb1[(size_t)(t + 2) * 64];
      asm volatile("s_waitcnt vmcnt(4)" ::: "memory");
    } else {
      asm volatile("s_waitcnt vmcnt(0)" ::: "memory");
    }
    __builtin_amdgcn_sched_barrier(0);
    __builtin_amdgcn_s_barrier();                      // B1 ready
    body(1, mB0, mB1);
    __builtin_amdgcn_s_barrier();                      // B1 readers done
  }

  // ---- epilogue: reduce l (additive), O /= l ----
  l_acc0 += __shfl_xor(l_acc0, 16, 64);
  l_acc0 += __shfl_xor(l_acc0, 32, 64);
  l_acc1 += __shfl_xor(l_acc1, 16, 64);
  l_acc1 += __shfl_xor(l_acc1, 32, 64);
  #pragma unroll
  for (int qa = 0; qa < 2; ++qa) {
    #pragma unroll
    for (int r = 0; r < 4; ++r) {
      const float li = 1.0f / __shfl(qa ? l_acc1 : l_acc0, 4 * lg + r, 64);
      float* orow = O + ((size_t)bh * Sc + q0 + w * 32 + qa * 16 + 4 * lg + r) * Dc + lc;
      #pragma unroll
      for (int nt = 0; nt < 4; ++nt)
        orow[nt * 16] = o_acc[qa][nt][r] * li;
    }
  }
}

// ---------------- Fallback (round-1 kernel, used if ws too small) ----------------
constexpr int LDSW = KVBLK + 8;

__global__ __launch_bounds__(256)
void attn_fwd_v1(const float* __restrict__ Q, const float* __restrict__ K,
                 const float* __restrict__ V, const int* __restrict__ M,
                 float* __restrict__ O)
{
  const int bid   = blockIdx.x;
  const int qtile = bid & 31;
  const int bh    = bid >> 5;
  const int b     = bh >> 4;

  const float* Qp = Q + ((size_t)bh * Sc + (size_t)qtile * 64) * Dc;
  const float* Kp = K + (size_t)bh * Sc * Dc;
  const float* Vp = V + (size_t)bh * Sc * Dc;
  const int*   Mp = M + (size_t)b * Sc * Sc + (size_t)qtile * 64 * Sc;
  float*       Op = O + ((size_t)bh * Sc + (size_t)qtile * 64) * Dc;

  __shared__ _Float16 Klds [KVBLK][LDSW];
  __shared__ _Float16 Vtlds[Dc]   [LDSW];
  __shared__ _Float16 Pl   [64]   [LDSW];

  const int tid = threadIdx.x;
  const int w   = tid >> 6;
  const int l   = tid & 63;
  const int lg  = l >> 4;
  const int lc  = l & 15;

  f16x8 qf[2];
  {
    const float qs = 0.125f * 1.4426950408889634f;
    const float* qrow = Qp + (size_t)(w * 16 + lc) * Dc + 8 * lg;
    #pragma unroll
    for (int ks = 0; ks < 2; ++ks) {
      f16x8 t;
      #pragma unroll
      for (int e = 0; e < 8; ++e) t[e] = (_Float16)(qrow[ks * 32 + e] * qs);
      qf[ks] = t;
    }
  }

  f32x4 o_acc[4];
  #pragma unroll
  for (int nt = 0; nt < 4; ++nt) o_acc[nt] = (f32x4){0.f, 0.f, 0.f, 0.f};
  float m_r[4], l_r[4];
  #pragma unroll
  for (int r = 0; r < 4; ++r) { m_r[r] = -3.0e38f; l_r[r] = 0.f; }
  const float NEGL = -1.4426950e9f;

  for (int kv = 0; kv < NKV; ++kv) {
    const float* Kt = Kp + (size_t)kv * KVBLK * Dc;
    const float* Vt = Vp + (size_t)kv * KVBLK * Dc;
    __syncthreads();
    {
      const int r = tid >> 2, c0 = (tid & 3) * 16;
      const float* src = Kt + (size_t)r * Dc + c0;
      f16x8 h0, h1;
      #pragma unroll
      for (int e = 0; e < 8; ++e) h0[e] = (_Float16)src[e];
      #pragma unroll
      for (int e = 0; e < 8; ++e) h1[e] = (_Float16)src[8 + e];
      *(f16x8*)&Klds[r][c0]     = h0;
      *(f16x8*)&Klds[r][c0 + 8] = h1;
    }
    {
      const int r0 = (tid >> 4) * 4, c0 = (tid & 15) * 4;
      float a_[4][4];
      #pragma unroll
      for (int i = 0; i < 4; ++i) {
        const float4 v4 = *(const float4*)(Vt + (size_t)(r0 + i) * Dc + c0);
        a_[i][0] = v4.x; a_[i][1] = v4.y; a_[i][2] = v4.z; a_[i][3] = v4.w;
      }
      #pragma unroll
      for (int j = 0; j < 4; ++j) {
        f16x4 t = {(_Float16)a_[0][j], (_Float16)a_[1][j],
                   (_Float16)a_[2][j], (_Float16)a_[3][j]};
        *(f16x4*)&Vtlds[c0 + j][r0] = t;
      }
    }
    __syncthreads();

    f32x4 s_acc[4];
    #pragma unroll
    for (int nt = 0; nt < 4; ++nt) {
      f32x4 acc = (f32x4){0.f, 0.f, 0.f, 0.f};
      #pragma unroll
      for (int ks = 0; ks < 2; ++ks) {
        f16x8 kf = *(const f16x8*)&Klds[nt * 16 + lc][ks * 32 + 8 * lg];
        acc = __builtin_amdgcn_mfma_f32_16x16x32_f16(qf[ks], kf, acc, 0, 0, 0);
      }
      s_acc[nt] = acc;
    }

    const int* mbase = Mp + (size_t)kv * KVBLK + lc;
    #pragma unroll
    for (int r = 0; r < 4; ++r) {
      const int qrow = w * 16 + 4 * lg + r;
      const int* mr = mbase + (size_t)qrow * Sc;
      float s0 = (mr[0]  != 0) ? s_acc[0][r] : NEGL;
      float s1 = (mr[16] != 0) ? s_acc[1][r] : NEGL;
      float s2 = (mr[32] != 0) ? s_acc[2][r] : NEGL;
      float s3 = (mr[48] != 0) ? s_acc[3][r] : NEGL;
      float mx = fmaxf(fmaxf(s0, s1), fmaxf(s2, s3));
      #pragma unroll
      for (int off = 1; off < 16; off <<= 1)
        mx = fmaxf(mx, __shfl_xor(mx, off, 64));
      const float mn   = fmaxf(m_r[r], mx);
      const float corr = fast_exp2(m_r[r] - mn);
      m_r[r] = mn;
      float p0 = fast_exp2(s0 - mn);
      float p1 = fast_exp2(s1 - mn);
      float p2 = fast_exp2(s2 - mn);
      float p3 = fast_exp2(s3 - mn);
      float rs = (p0 + p1) + (p2 + p3);
      #pragma unroll
      for (int off = 1; off < 16; off <<= 1)
        rs += __shfl_xor(rs, off, 64);
      l_r[r] = l_r[r] * corr + rs;
      #pragma unroll
      for (int nt = 0; nt < 4; ++nt) o_acc[nt][r] *= corr;
      Pl[qrow][lc]      = (_Float16)p0;
      Pl[qrow][16 + lc] = (_Float16)p1;
      Pl[qrow][32 + lc] = (_Float16)p2;
      Pl[qrow][48 + lc] = (_Float16)p3;
    }

    #pragma unroll
    for (int nt = 0; nt < 4; ++nt) {
      #pragma unroll
      for (int ks = 0; ks < 2; ++ks) {
        f16x8 pf = *(const f16x8*)&Pl[w * 16 + lc][ks * 32 + 8 * lg];
        f16x8 vf = *(const f16x8*)&Vtlds[nt * 16 + lc][ks * 32 + 8 * lg];
        o_acc[nt] = __builtin_amdgcn_mfma_f32_16x16x32_f16(pf, vf, o_acc[nt], 0, 0, 0);
      }
    }
  }

  #pragma unroll
  for (int r = 0; r < 4; ++r) {
    const float inv = 1.0f / l_r[r];
    float* orow = Op + (size_t)(w * 16 + 4 * lg + r) * Dc;
    #pragma unroll
    for (int nt = 0; nt < 4; ++nt)
      orow[nt * 16 + lc] = o_acc[nt][r] * inv;
  }
}

extern "C" void kernel_launch(void* const* d_in, const int* in_sizes, int n_in,
                              void* d_out, int out_size, void* d_ws, size_t ws_size,
                              hipStream_t stream) {
  (void)in_sizes; (void)n_in; (void)out_size;
  const float* Q = (const float*)d_in[0];
  const float* K = (const float*)d_in[1];
  const float* V = (const float*)d_in[2];
  const int*   M = (const int*)d_in[3];
  float*       O = (float*)d_out;

  const size_t nKV      = (size_t)Bc * Hc * Sc * Dc;        // 8,388,608
  const size_t bytesK16 = nKV * 2;                           // 16 MiB
  const size_t bytesMB  = (size_t)Bc * NQ * NKV * 64 * 8;    // 2 MiB
  const size_t need     = 2 * bytesK16 + bytesMB;

  if (ws_size >= need) {
    _Float16* K16  = (_Float16*)d_ws;
    _Float16* Vt16 = (_Float16*)((char*)d_ws + bytesK16);
    u64*      MBp  = (u64*)((char*)d_ws + 2 * bytesK16);
    hipLaunchKernelGGL(cvt_k_sw,   dim3(2048),  dim3(256), 0, stream, K, K16);
    hipLaunchKernelGGL(cvt_v_sw,   dim3(2048),  dim3(256), 0, stream, V, Vt16);
    hipLaunchKernelGGL(pack_mask,  dim3(65536), dim3(256), 0, stream, M, MBp);
    hipLaunchKernelGGL(attn_fwd11, dim3(512),   dim3(512), 0, stream, Q, K16, Vt16, MBp, O);
  } else {
    hipLaunchKernelGGL(attn_fwd_v1, dim3(2048), dim3(256), 0, stream, Q, K, V, M, O);
  }
}